// Round 1
// baseline (11462.914 us; speedup 1.0000x reference)
//
#include <hip/hip_runtime.h>

#define Tn 1024
#define Fn 64
#define Un 256
#define Gn 1024
#define Kn 320
#define BCn 16
#define NBLK 32
#define AS 328   // padded A row stride in ushorts (2-way-free LDS banking, 16B aligned)

typedef __attribute__((ext_vector_type(8))) short bf16x8;
typedef __attribute__((ext_vector_type(8))) unsigned short ushort8;
typedef __attribute__((ext_vector_type(4))) float f32x4;

__device__ __forceinline__ float bf2f(unsigned short u){
  union { unsigned int i; float f; } v; v.i = ((unsigned int)u) << 16; return v.f;
}
__device__ __forceinline__ unsigned short f2bf(float f){
  unsigned int u = __float_as_uint(f);
  u += 0x7FFFu + ((u >> 16) & 1u);   // RNE
  return (unsigned short)(u >> 16);
}
__device__ __forceinline__ float load_f(const void* p, long idx, int isf32){
  if (isf32) return ((const float*)p)[idx];
  return bf2f(((const unsigned short*)p)[idx]);
}
__device__ __forceinline__ float sigm(float x){
  return 1.0f / (1.0f + __expf(-x));
}
__device__ __forceinline__ float tanh_f(float x){
  return 2.0f * sigm(2.0f * x) - 1.0f;
}

// ---------------------------------------------------------------------------
// Kernel 0: runtime dtype probe. Read x as a bf16 stream; genuine bf16 N(0,1)
// data gives |v| < ~6 always. fp32 N(0,1) data makes every low-half ushort
// decode to garbage (random exponent) -> ~half the samples have |v|>100/NaN.
__global__ void detect_dtype(const void* x, int* flag){
  int l = threadIdx.x;
  int cnt = 0;
  for (int s = 0; s < 4; ++s){
    float v = bf2f(((const unsigned short*)x)[l + 64*s]);
    if (!(fabsf(v) <= 100.0f)) cnt++;   // catches NaN too
  }
  for (int off = 32; off > 0; off >>= 1) cnt += __shfl_down(cnt, off);
  if (l == 0) *flag = (cnt > 32) ? 1 : 0;   // 1 => inputs are fp32
}

// ---------------------------------------------------------------------------
// Kernel 1: pack [Uh; W] (K=320 x G=1024) into MFMA-B-fragment order, with a
// column permutation so wave w owns all 4 gates of units [w*16, w*16+16):
//   packed col n: w = n>>6, g = (n>>4)&3, ul = n&15  ->  orig col g*256 + w*16 + ul
// Fragment storage: flat = ((kt*1024 + n)*4 + q)*8 + j, k = kt*32 + q*8 + j.
// Lane l of a frag then does ONE 16B load at (l&15)*64 + (l>>4)*16 bytes.
__global__ void reformat_w(const void* Uh, const void* W, unsigned short* Bp, const int* flag){
  int isf32 = *flag;
  int gidx = blockIdx.x * blockDim.x + threadIdx.x;   // 0..40959
  if (gidx >= 40960) return;
  int kt  = gidx >> 12;
  int rem = gidx & 4095;
  int n   = rem >> 2;
  int q   = rem & 3;
  int grp = n >> 6;
  int g   = (n >> 4) & 3;
  int ul  = n & 15;
  int col = g*256 + grp*16 + ul;
  unsigned short vals[8];
  #pragma unroll
  for (int j = 0; j < 8; ++j){
    int k = kt*32 + q*8 + j;
    float v = (k < Un) ? load_f(Uh, (long)k*Gn + col, isf32)
                       : load_f(W,  (long)(k-Un)*Gn + col, isf32);
    vals[j] = f2bf(v);
  }
  *(ushort8*)(Bp + (long)gidx * 8) = *(ushort8*)vals;
}

// ---------------------------------------------------------------------------
// Kernel 2: persistent LSTM. 32 blocks x 1024 threads (16 waves), 16 batches
// per block. Per step: z = [h|x_t](16x320) @ packedW(320x1024) via
// mfma_f32_16x16x32_bf16 (wave w owns 64 cols = 4 gates x 16 units; 10 K-tiles
// x 4 N-frags = 40 MFMA/wave). B-frags streamed from L2, double-buffered per
// K-tile. A double-buffered in LDS; x_{t+1} prefetched during compute; ONE
// __syncthreads per step. Epilogue: out[b,t] = sigmoid(h_T . dense_w + db).
__global__ __launch_bounds__(1024) void lstm_attn(
    const void* x, const void* bvec, const void* dense_w, const void* dense_b,
    const unsigned short* Bp, const int* flag, void* out)
{
  __shared__ __align__(16) unsigned short A_s[2][16*AS];
  __shared__ float ps[16][16];
  __shared__ float outv[16];

  const int isf32 = *flag;
  const int tid = threadIdx.x;
  const int w   = tid >> 6;
  const int l   = tid & 63;
  const int bc  = blockIdx.x;
  const int l15 = l & 15;
  const int q   = l >> 4;

  // zero h region of buffer 0 (h0 = 0)
  for (int i = tid; i < 16*Un; i += 1024)
    A_s[0][(i >> 8)*AS + (i & 255)] = 0;

  // load x_0 into buffer 0 cols [256,320)
  if (tid < 128){
    int m = tid >> 3, ch = tid & 7;
    long src = ((long)(bc*BCn + m)*Tn + 0)*Fn + ch*8;
    unsigned short v[8];
    if (isf32){
      #pragma unroll
      for (int j = 0; j < 8; ++j) v[j] = f2bf(((const float*)x)[src + j]);
    } else {
      *(ushort8*)v = *(const ushort8*)((const unsigned short*)x + src);
    }
    *(ushort8*)&A_s[0][m*AS + Un + ch*8] = *(ushort8*)v;
  }

  float bias[4];
  #pragma unroll
  for (int g = 0; g < 4; ++g) bias[g] = load_f(bvec, g*Un + w*16 + l15, isf32);

  float c[4]    = {0.f, 0.f, 0.f, 0.f};
  float hreg[4] = {0.f, 0.f, 0.f, 0.f};

  // per-thread base into packed weights for this wave's 64 columns
  const char* Bw = (const char*)Bp + (long)(w*64)*64 + (l15*64 + q*16);

  __syncthreads();

  for (int t = 0; t < Tn; ++t){
    const int buf = t & 1, nbuf = buf ^ 1;

    // prefetch x_{t+1} into the other buffer (waves 0-1 only; uniform per wave)
    if (tid < 128 && (t+1) < Tn){
      int m = tid >> 3, ch = tid & 7;
      long src = ((long)(bc*BCn + m)*Tn + (t+1))*Fn + ch*8;
      unsigned short v[8];
      if (isf32){
        #pragma unroll
        for (int j = 0; j < 8; ++j) v[j] = f2bf(((const float*)x)[src + j]);
      } else {
        *(ushort8*)v = *(const ushort8*)((const unsigned short*)x + src);
      }
      *(ushort8*)&A_s[nbuf][m*AS + Un + ch*8] = *(ushort8*)v;
    }

    f32x4 acc[4];
    #pragma unroll
    for (int g = 0; g < 4; ++g) acc[g] = (f32x4){0.f, 0.f, 0.f, 0.f};

    bf16x8 breg[2][4];
    #pragma unroll
    for (int nt = 0; nt < 4; ++nt)
      breg[0][nt] = *(const bf16x8*)(Bw + (long)(nt*16)*64);

    #pragma unroll
    for (int kt = 0; kt < 10; ++kt){
      const int cur = kt & 1;
      if (kt < 9){
        #pragma unroll
        for (int nt = 0; nt < 4; ++nt)
          breg[cur^1][nt] = *(const bf16x8*)(Bw + (long)((kt+1)*1024 + nt*16)*64);
      }
      bf16x8 af = *(const bf16x8*)&A_s[buf][l15*AS + kt*32 + q*8];
      #pragma unroll
      for (int nt = 0; nt < 4; ++nt)
        acc[nt] = __builtin_amdgcn_mfma_f32_16x16x32_bf16(af, breg[cur][nt], acc[nt], 0, 0, 0);
    }

    // gates: acc[g][r] = z[m = q*4+r][gate g, unit u = w*16+l15]
    #pragma unroll
    for (int r = 0; r < 4; ++r){
      float zi = acc[0][r] + bias[0];
      float zf = acc[1][r] + bias[1];
      float zg = acc[2][r] + bias[2];
      float zo = acc[3][r] + bias[3];
      float ig = sigm(zi);
      float fg = sigm(zf);
      float gg = tanh_f(zg);
      float og = sigm(zo);
      float cn = fg * c[r] + ig * gg;
      c[r] = cn;
      float hn = og * tanh_f(cn);
      hreg[r] = hn;
      A_s[nbuf][(q*4 + r)*AS + (w*16 + l15)] = f2bf(hn);
    }
    __syncthreads();
  }

  // epilogue: logits[m] = sum_u h_T[m][u] * dense_w[u] + dense_b; out = sigmoid
  float dwv = load_f(dense_w, w*16 + l15, isf32);
  float p[4];
  #pragma unroll
  for (int r = 0; r < 4; ++r){
    p[r] = hreg[r] * dwv;
    #pragma unroll
    for (int s = 1; s < 16; s <<= 1) p[r] += __shfl_xor(p[r], s);
  }
  if (l15 == 0){
    #pragma unroll
    for (int r = 0; r < 4; ++r) ps[w][q*4 + r] = p[r];
  }
  __syncthreads();
  if (tid < 16){
    float s = load_f(dense_b, 0, isf32);
    #pragma unroll
    for (int wv = 0; wv < 16; ++wv) s += ps[wv][tid];
    outv[tid] = sigm(s);
  }
  __syncthreads();

  // broadcast h_T-derived scalar across all T: 16 rows x 1024 coalesced writes
  for (int m = 0; m < 16; ++m){
    float v = outv[m];
    long base = (long)(bc*BCn + m) * Tn + tid;
    if (isf32) ((float*)out)[base] = v;
    else       ((unsigned short*)out)[base] = f2bf(v);
  }
}

// ---------------------------------------------------------------------------
extern "C" void kernel_launch(void* const* d_in, const int* in_sizes, int n_in,
                              void* d_out, int out_size, void* d_ws, size_t ws_size,
                              hipStream_t stream){
  const void* x  = d_in[0];
  const void* W  = d_in[1];
  const void* Uh = d_in[2];
  const void* b  = d_in[3];
  const void* dw = d_in[4];
  const void* db = d_in[5];

  int* flag = (int*)d_ws;
  unsigned short* Bp = (unsigned short*)((char*)d_ws + 256);  // 655360 B packed weights

  detect_dtype<<<1, 64, 0, stream>>>(x, flag);
  reformat_w<<<160, 256, 0, stream>>>(Uh, W, Bp, flag);
  lstm_attn<<<NBLK, 1024, 0, stream>>>(x, b, dw, db, Bp, flag, d_out);
}

// Round 2
// 3631.456 us; speedup vs baseline: 3.1566x; 3.1566x over previous
//
#include <hip/hip_runtime.h>

#define Tn 1024
#define Fn 64
#define Un 256
#define Gn 1024
#define AS 328       // padded A row stride (ushorts): 656 B -> balanced LDS banking
#define GROUPS 32
#define THREADS 512

typedef __attribute__((ext_vector_type(8))) short bf16x8;
typedef __attribute__((ext_vector_type(8))) unsigned short ushort8;
typedef __attribute__((ext_vector_type(4))) float f32x4;

// ws layout (bytes):
//   [0,      4096) : int flags[64*16]  — per-block step flag, 64 B apart
//   [4096,   4100) : dtype flag (1 = inputs are fp32)
//   [8192, 532480) : xchg — (group,half,parity) chunks, 128 x 4096 B, u64-addressed
//   [532480, ... ) : packed weights Bp, 655360 B
#define WS_DT    1024          // int index of dtype flag
#define WS_XCHG  8192
#define WS_BP    532480

__device__ __forceinline__ float bf2f(unsigned short u){
  union { unsigned int i; float f; } v; v.i = ((unsigned int)u) << 16; return v.f;
}
__device__ __forceinline__ unsigned short f2bf(float f){
  unsigned int u = __float_as_uint(f);
  u += 0x7FFFu + ((u >> 16) & 1u);
  return (unsigned short)(u >> 16);
}
__device__ __forceinline__ float load_f(const void* p, long idx, int isf32){
  if (isf32) return ((const float*)p)[idx];
  return bf2f(((const unsigned short*)p)[idx]);
}
__device__ __forceinline__ float sigm(float x){ return 1.0f / (1.0f + __expf(-x)); }
__device__ __forceinline__ float tanh_f(float x){ return 2.0f * sigm(2.0f * x) - 1.0f; }

// ---------------------------------------------------------------------------
// init: zero flags + runtime dtype probe (bf16 N(0,1) never decodes |v|>100)
__global__ void init_k(const void* x, int* wsi){
  int tid = threadIdx.x;
  for (int i = tid; i < 1024; i += 256) wsi[i] = 0;
  if (tid < 64){
    int cnt = 0;
    for (int s2 = 0; s2 < 4; ++s2){
      float v = bf2f(((const unsigned short*)x)[tid + 64*s2]);
      if (!(fabsf(v) <= 100.0f)) cnt++;
    }
    for (int off = 32; off > 0; off >>= 1) cnt += __shfl_down(cnt, off);
    if (tid == 0) wsi[WS_DT] = (cnt > 32) ? 1 : 0;
  }
}

// ---------------------------------------------------------------------------
// pack [Uh; W] (K=320 x 1024) into B-fragment order, columns permuted so
// block-half s, wave w owns all 4 gates of units s*128 + w*16 .. +16:
//   packed n: half=n>>9, w=(n>>6)&7, g=(n>>4)&3, ul=n&15
//   orig col = g*256 + half*128 + w*16 + ul
// frag storage: ushort flat = ((kt*1024 + n)*4 + q)*8 + j, k = kt*32+q*8+j
__global__ void reformat_w(const void* Uh, const void* W, unsigned short* Bp, const int* dt){
  int isf32 = *dt;
  int gidx = blockIdx.x * blockDim.x + threadIdx.x;
  if (gidx >= 40960) return;
  int kt  = gidx >> 12;
  int rem = gidx & 4095;
  int n   = rem >> 2;
  int q   = rem & 3;
  int half = n >> 9;
  int w    = (n >> 6) & 7;
  int g    = (n >> 4) & 3;
  int ul   = n & 15;
  int col  = g*256 + half*128 + w*16 + ul;
  unsigned short vals[8];
  #pragma unroll
  for (int j = 0; j < 8; ++j){
    int k = kt*32 + q*8 + j;
    float v = (k < Un) ? load_f(Uh, (long)k*Gn + col, isf32)
                       : load_f(W,  (long)(k-Un)*Gn + col, isf32);
    vals[j] = f2bf(v);
  }
  *(ushort8*)(Bp + (long)gidx * 8) = *(ushort8*)vals;
}

// ---------------------------------------------------------------------------
// Persistent LSTM, 64 blocks x 512 threads. Block = (group g = bid>>1, half
// s = bid&1). Weights for this block's 512 gate-cols live ENTIRELY in VGPRs
// (wfrag[10][4], 160 VGPRs/thread). Per step: MFMA own-h + x tiles while the
// partner's 4 KB h-chunk flies in from the Infinity Cache (agent-scope
// atomics), then partner tiles, gates, publish own chunk with release flag.
// K-row order: rows 0..255 = h units, 256..319 = x.  wfrag slot order:
// [0..3]=own h kts, [4..5]=x kts(8,9), [6..9]=partner h kts.
__global__ __launch_bounds__(THREADS, 2) void lstm_k(
    const void* x, const void* bvec, const void* dense_w, const void* dense_b,
    const unsigned short* Bp, const int* dt, int* flags, unsigned long long* xchg,
    void* out)
{
  __shared__ __align__(16) unsigned short A_s[2][16*AS];
  __shared__ float outv[16];

  const int isf32 = *dt;
  const int tid = threadIdx.x;
  const int w   = tid >> 6;
  const int l   = tid & 63;
  const int l15 = l & 15;
  const int q   = l >> 4;
  const int g   = blockIdx.x >> 1;
  const int s   = blockIdx.x & 1;
  const int p   = s ^ 1;

  int* flag_me = flags + (g*2 + s)*16;
  int* flag_pr = flags + (g*2 + p)*16;

  // ---- load this wave's weights into registers (compile-time slots) ----
  const char* Bb = (const char*)Bp + (long)(l15*64 + q*16);
  const int nbase = s*512 + w*64;
  bf16x8 wfrag[10][4];
  {
    int ktp[10];
    #pragma unroll
    for (int i = 0; i < 4; ++i) ktp[i] = s*4 + i;
    ktp[4] = 8; ktp[5] = 9;
    #pragma unroll
    for (int i = 0; i < 4; ++i) ktp[6+i] = p*4 + i;
    #pragma unroll
    for (int i = 0; i < 10; ++i){
      #pragma unroll
      for (int nt = 0; nt < 4; ++nt)
        wfrag[i][nt] = *(const bf16x8*)(Bb + (long)(ktp[i]*1024 + nbase + nt*16)*64);
    }
  }

  // zero h region of buffer 0 (h0 = 0, both halves)
  for (int i = tid; i < 16*Un; i += THREADS)
    A_s[0][(i >> 8)*AS + (i & 255)] = 0;

  // x_0 -> buffer 0 cols [256,320)
  if (tid < 128){
    int m = tid >> 3, ch = tid & 7;
    long src = ((long)(g*16 + m)*Tn + 0)*Fn + ch*8;
    unsigned short v[8];
    if (isf32){ for (int j = 0; j < 8; ++j) v[j] = f2bf(((const float*)x)[src + j]); }
    else      { *(ushort8*)v = *(const ushort8*)((const unsigned short*)x + src); }
    *(ushort8*)&A_s[0][m*AS + Un + ch*8] = *(ushort8*)v;
  }

  float bias[4];
  #pragma unroll
  for (int gg = 0; gg < 4; ++gg) bias[gg] = load_f(bvec, gg*256 + s*128 + w*16 + l15, isf32);

  float c[4]    = {0.f, 0.f, 0.f, 0.f};
  float hreg[4] = {0.f, 0.f, 0.f, 0.f};

  __syncthreads();

  for (int t = 0; t < Tn; ++t){
    const int buf = t & 1, nbuf = buf ^ 1;

    // (a) x_{t+1} into regs
    unsigned short xv[8];
    if (tid < 128 && (t+1) < Tn){
      int m = tid >> 3, ch = tid & 7;
      long src = ((long)(g*16 + m)*Tn + (t+1))*Fn + ch*8;
      if (isf32){ for (int j = 0; j < 8; ++j) xv[j] = f2bf(((const float*)x)[src + j]); }
      else      { *(ushort8*)xv = *(const ushort8*)((const unsigned short*)x + src); }
    }

    // (poll) partner published h^t?
    if (t > 0 && tid == 0){
      while (__hip_atomic_load(flag_pr, __ATOMIC_RELAXED, __HIP_MEMORY_SCOPE_AGENT) < t) {}
    }
    __syncthreads();   // barrier 1: flag seen by all

    // issue partner chunk load (IC latency hides under own-half MFMA)
    unsigned long long chunk = 0ULL;
    if (t > 0){
      const unsigned long long* src = xchg + (((size_t)((g*2 + p)*2 + buf)) << 9) + tid;
      chunk = __hip_atomic_load(src, __ATOMIC_RELAXED, __HIP_MEMORY_SCOPE_AGENT);
    }

    // (b) MFMA own-h (slots 0..3) + x (slots 4,5)
    f32x4 acc[4];
    #pragma unroll
    for (int nt = 0; nt < 4; ++nt) acc[nt] = (f32x4){0.f, 0.f, 0.f, 0.f};
    {
      const int kb = s*4;
      #pragma unroll
      for (int i = 0; i < 4; ++i){
        bf16x8 af = *(const bf16x8*)&A_s[buf][l15*AS + (kb + i)*32 + q*8];
        #pragma unroll
        for (int nt = 0; nt < 4; ++nt)
          acc[nt] = __builtin_amdgcn_mfma_f32_16x16x32_bf16(af, wfrag[i][nt], acc[nt], 0, 0, 0);
      }
      #pragma unroll
      for (int i = 4; i < 6; ++i){
        bf16x8 af = *(const bf16x8*)&A_s[buf][l15*AS + (4 + i)*32 + q*8];  // kt = 8,9
        #pragma unroll
        for (int nt = 0; nt < 4; ++nt)
          acc[nt] = __builtin_amdgcn_mfma_f32_16x16x32_bf16(af, wfrag[i][nt], acc[nt], 0, 0, 0);
      }
    }

    // scatter partner chunk into A_s[buf] partner cols
    if (t > 0){
      int u = tid >> 2, r0 = (tid & 3) * 4;
      #pragma unroll
      for (int i = 0; i < 4; ++i)
        A_s[buf][(r0 + i)*AS + p*128 + u] = (unsigned short)(chunk >> (16*i));
    }
    // stage x_{t+1}
    if (tid < 128 && (t+1) < Tn){
      int m = tid >> 3, ch = tid & 7;
      *(ushort8*)&A_s[nbuf][m*AS + Un + ch*8] = *(ushort8*)xv;
    }
    __syncthreads();   // barrier 2: partner cols ready

    // (d) MFMA partner-h (slots 6..9)
    {
      const int kb = p*4;
      #pragma unroll
      for (int i = 0; i < 4; ++i){
        bf16x8 af = *(const bf16x8*)&A_s[buf][l15*AS + (kb + i)*32 + q*8];
        #pragma unroll
        for (int nt = 0; nt < 4; ++nt)
          acc[nt] = __builtin_amdgcn_mfma_f32_16x16x32_bf16(af, wfrag[6+i][nt], acc[nt], 0, 0, 0);
      }
    }

    // (e) gates; acc[g][r] = z[row q*4+r][gate g, unit s*128+w*16+l15]
    unsigned short hb[4];
    #pragma unroll
    for (int r = 0; r < 4; ++r){
      float zi = acc[0][r] + bias[0];
      float zf = acc[1][r] + bias[1];
      float zg = acc[2][r] + bias[2];
      float zo = acc[3][r] + bias[3];
      float ig = sigm(zi);
      float fg = sigm(zf);
      float gg = tanh_f(zg);
      float og = sigm(zo);
      float cn = fg * c[r] + ig * gg;
      c[r] = cn;
      float hn = og * tanh_f(cn);
      hreg[r] = hn;
      hb[r] = f2bf(hn);
      A_s[nbuf][(q*4 + r)*AS + (s*128 + w*16 + l15)] = hb[r];
    }
    // publish own chunk h^{t+1}: u64 per thread, [unit][row] layout
    {
      unsigned long long val = (unsigned long long)hb[0]
                             | ((unsigned long long)hb[1] << 16)
                             | ((unsigned long long)hb[2] << 32)
                             | ((unsigned long long)hb[3] << 48);
      int u_loc = w*16 + l15;
      unsigned long long* dst = xchg + (((size_t)((g*2 + s)*2 + ((t+1) & 1))) << 9) + u_loc*4 + q;
      __hip_atomic_store(dst, val, __ATOMIC_RELAXED, __HIP_MEMORY_SCOPE_AGENT);
    }
    __syncthreads();   // barrier 3: all chunk stores vmcnt-drained
    if (tid == 0)
      __hip_atomic_store(flag_me, t+1, __ATOMIC_RELEASE, __HIP_MEMORY_SCOPE_AGENT);
  }

  // ---- epilogue: only half-0 blocks assemble h_T and write output ----
  if (s == 0){
    if (tid == 0){
      while (__hip_atomic_load(flag_pr, __ATOMIC_RELAXED, __HIP_MEMORY_SCOPE_AGENT) < Tn) {}
    }
    __syncthreads();
    {
      const unsigned long long* src = xchg + (((size_t)((g*2 + 1)*2 + 0)) << 9) + tid;
      unsigned long long chunk = __hip_atomic_load(src, __ATOMIC_RELAXED, __HIP_MEMORY_SCOPE_AGENT);
      int u = tid >> 2, r0 = (tid & 3) * 4;
      #pragma unroll
      for (int i = 0; i < 4; ++i)
        A_s[0][(r0 + i)*AS + 128 + u] = (unsigned short)(chunk >> (16*i));
    }
    __syncthreads();

    int m = tid >> 5, j = tid & 31;
    float partial = 0.f;
    for (int u = j; u < 256; u += 32)
      partial += bf2f(A_s[0][m*AS + u]) * load_f(dense_w, u, isf32);
    #pragma unroll
    for (int off = 1; off < 32; off <<= 1) partial += __shfl_xor(partial, off);
    if (j == 0) outv[m] = sigm(partial + load_f(dense_b, 0, isf32));
    __syncthreads();

    for (int mm = 0; mm < 16; ++mm){
      float v = outv[mm];
      long base = (long)(g*16 + mm) * Tn;
      for (int col = tid; col < Tn; col += THREADS){
        if (isf32) ((float*)out)[base + col] = v;
        else       ((unsigned short*)out)[base + col] = f2bf(v);
      }
    }
  }
}

// ---------------------------------------------------------------------------
extern "C" void kernel_launch(void* const* d_in, const int* in_sizes, int n_in,
                              void* d_out, int out_size, void* d_ws, size_t ws_size,
                              hipStream_t stream){
  const void* x  = d_in[0];
  const void* W  = d_in[1];
  const void* Uh = d_in[2];
  const void* b  = d_in[3];
  const void* dw = d_in[4];
  const void* db = d_in[5];

  int* wsi = (int*)d_ws;
  int* flags = wsi;
  const int* dt = wsi + WS_DT;
  unsigned long long* xchg = (unsigned long long*)((char*)d_ws + WS_XCHG);
  unsigned short* Bp = (unsigned short*)((char*)d_ws + WS_BP);

  init_k<<<1, 256, 0, stream>>>(x, wsi);
  reformat_w<<<160, 256, 0, stream>>>(Uh, W, Bp, dt);
  lstm_k<<<GROUPS*2, THREADS, 0, stream>>>(x, b, dw, db, Bp, dt, flags, xchg, d_out);
}

// Round 3
// 2996.962 us; speedup vs baseline: 3.8248x; 1.2117x over previous
//
#include <hip/hip_runtime.h>

#define Tn 1024
#define Fn 64
#define Un 256
#define Gn 1024
#define AS 328       // padded A row stride (ushorts)
#define GROUPS 32
#define THREADS 512

typedef __attribute__((ext_vector_type(8))) short bf16x8;
typedef __attribute__((ext_vector_type(8))) unsigned short ushort8;
typedef __attribute__((ext_vector_type(4))) float f32x4;

// ws layout (bytes):
//   [0,    4096) : int hdr — dtype flag at int index 0
//   [4096, 4096 + 64*2*8192) : xchg — per block, 2 parity slots x 2048 tagged
//                  u32s (value = bf16<<16 | step-tag). 1 MiB total.
//   [WS_BP, +655360) : packed weights Bp
#define WS_XCHG 4096
#define WS_BP   (WS_XCHG + 64*2*8192)

__device__ __forceinline__ float bf2f(unsigned short u){
  union { unsigned int i; float f; } v; v.i = ((unsigned int)u) << 16; return v.f;
}
__device__ __forceinline__ unsigned short f2bf(float f){
  unsigned int u = __float_as_uint(f);
  u += 0x7FFFu + ((u >> 16) & 1u);
  return (unsigned short)(u >> 16);
}
__device__ __forceinline__ float load_f(const void* p, long idx, int isf32){
  if (isf32) return ((const float*)p)[idx];
  return bf2f(((const unsigned short*)p)[idx]);
}
__device__ __forceinline__ float sigm(float x){ return 1.0f / (1.0f + __expf(-x)); }
__device__ __forceinline__ float tanh_f(float x){ return 2.0f * sigm(2.0f * x) - 1.0f; }

// ---------------------------------------------------------------------------
__global__ void init_k(const void* x, int* wsi){
  int tid = threadIdx.x;
  if (tid < 64){
    int cnt = 0;
    for (int s2 = 0; s2 < 4; ++s2){
      float v = bf2f(((const unsigned short*)x)[tid + 64*s2]);
      if (!(fabsf(v) <= 100.0f)) cnt++;
    }
    for (int off = 32; off > 0; off >>= 1) cnt += __shfl_down(cnt, off);
    if (tid == 0) wsi[0] = (cnt > 32) ? 1 : 0;   // 1 => inputs are fp32
  }
}

// ---------------------------------------------------------------------------
// pack [Uh; W] (K=320 x 1024) into B-fragment order (identical to round 2):
//   packed n: half=n>>9, w=(n>>6)&7, g=(n>>4)&3, ul=n&15
//   orig col = g*256 + half*128 + w*16 + ul
__global__ void reformat_w(const void* Uh, const void* W, unsigned short* Bp, const int* dt){
  int isf32 = *dt;
  int gidx = blockIdx.x * blockDim.x + threadIdx.x;
  if (gidx >= 40960) return;
  int kt  = gidx >> 12;
  int rem = gidx & 4095;
  int n   = rem >> 2;
  int q   = rem & 3;
  int half = n >> 9;
  int w    = (n >> 6) & 7;
  int g    = (n >> 4) & 3;
  int ul   = n & 15;
  int col  = g*256 + half*128 + w*16 + ul;
  unsigned short vals[8];
  #pragma unroll
  for (int j = 0; j < 8; ++j){
    int k = kt*32 + q*8 + j;
    float v = (k < Un) ? load_f(Uh, (long)k*Gn + col, isf32)
                       : load_f(W,  (long)(k-Un)*Gn + col, isf32);
    vals[j] = f2bf(v);
  }
  *(ushort8*)(Bp + (long)gidx * 8) = *(ushort8*)vals;
}

// ---------------------------------------------------------------------------
// Persistent LSTM, 64 blocks x 512 threads, half-split N. Exchange protocol:
// tag-in-data, relaxed agent-scope u32s, one fabric round trip per step.
// xchg word layout per slot: flat = row*128 + unit_local (row 0..15).
__global__ __launch_bounds__(THREADS, 2) void lstm_k(
    const void* x, const void* bvec, const void* dense_w, const void* dense_b,
    const unsigned short* Bp, const int* dt, unsigned int* xchg, void* out)
{
  __shared__ __align__(16) unsigned short A_s[2][16*AS];
  __shared__ float outv[16];

  const int isf32 = *dt;
  const int tid = threadIdx.x;
  const int w   = tid >> 6;
  const int l   = tid & 63;
  const int l15 = l & 15;
  const int q   = l >> 4;
  const int g   = blockIdx.x >> 1;
  const int s   = blockIdx.x & 1;
  const int p   = s ^ 1;

  unsigned int*       xc_me = xchg + (size_t)(g*2 + s) * 4096;
  const unsigned int* xc_pr = xchg + (size_t)(g*2 + p) * 4096;

  // ---- weights into registers (compiler places in unified VGPR/AGPR file) --
  const char* Bb = (const char*)Bp + (long)(l15*64 + q*16);
  const int nbase = s*512 + w*64;
  bf16x8 wfrag[10][4];
  {
    int ktp[10];
    #pragma unroll
    for (int i = 0; i < 4; ++i) ktp[i] = s*4 + i;
    ktp[4] = 8; ktp[5] = 9;
    #pragma unroll
    for (int i = 0; i < 4; ++i) ktp[6+i] = p*4 + i;
    #pragma unroll
    for (int i = 0; i < 10; ++i){
      #pragma unroll
      for (int nt = 0; nt < 4; ++nt)
        wfrag[i][nt] = *(const bf16x8*)(Bb + (long)(ktp[i]*1024 + nbase + nt*16)*64);
    }
  }

  // zero h region of buffer 0
  for (int i = tid; i < 16*Un; i += THREADS)
    A_s[0][(i >> 8)*AS + (i & 255)] = 0;

  // x_0 -> buffer 0 cols [256,320)
  if (tid < 128){
    int m = tid >> 3, ch = tid & 7;
    long src = ((long)(g*16 + m)*Tn + 0)*Fn + ch*8;
    unsigned short v[8];
    if (isf32){ for (int j = 0; j < 8; ++j) v[j] = f2bf(((const float*)x)[src + j]); }
    else      { *(ushort8*)v = *(const ushort8*)((const unsigned short*)x + src); }
    *(ushort8*)&A_s[0][m*AS + Un + ch*8] = *(ushort8*)v;
  }

  float bias[4];
  #pragma unroll
  for (int gg = 0; gg < 4; ++gg) bias[gg] = load_f(bvec, gg*256 + s*128 + w*16 + l15, isf32);

  float c[4] = {0.f, 0.f, 0.f, 0.f};

  __syncthreads();

  for (int t = 0; t < Tn; ++t){
    const int buf = t & 1, nbuf = buf ^ 1;

    // (1) x_{t+1} into regs
    unsigned short xv[8];
    if (tid < 128 && (t+1) < Tn){
      int m = tid >> 3, ch = tid & 7;
      long src = ((long)(g*16 + m)*Tn + (t+1))*Fn + ch*8;
      if (isf32){ for (int j = 0; j < 8; ++j) xv[j] = f2bf(((const float*)x)[src + j]); }
      else      { *(ushort8*)xv = *(const ushort8*)((const unsigned short*)x + src); }
    }

    // (2) MFMA own-h (slots 0..3) + x (slots 4,5); bias folded into acc init
    f32x4 acc[4];
    #pragma unroll
    for (int nt = 0; nt < 4; ++nt)
      acc[nt] = (f32x4){bias[nt], bias[nt], bias[nt], bias[nt]};
    {
      const int kb = s*4;
      #pragma unroll
      for (int i = 0; i < 4; ++i){
        bf16x8 af = *(const bf16x8*)&A_s[buf][l15*AS + (kb + i)*32 + q*8];
        #pragma unroll
        for (int nt = 0; nt < 4; ++nt)
          acc[nt] = __builtin_amdgcn_mfma_f32_16x16x32_bf16(af, wfrag[i][nt], acc[nt], 0, 0, 0);
      }
      #pragma unroll
      for (int i = 4; i < 6; ++i){
        bf16x8 af = *(const bf16x8*)&A_s[buf][l15*AS + (4 + i)*32 + q*8];  // kt = 8,9
        #pragma unroll
        for (int nt = 0; nt < 4; ++nt)
          acc[nt] = __builtin_amdgcn_mfma_f32_16x16x32_bf16(af, wfrag[i][nt], acc[nt], 0, 0, 0);
      }
    }

    // (3) poll partner words (tag == t), one round trip; own MFMA hides latency
    if (t > 0){
      const unsigned long long* src =
          (const unsigned long long*)(xc_pr + (size_t)buf*2048 + tid*4);
      const unsigned long long need = (unsigned long long)(t & 0xFFFF);
      unsigned int pv[4];
      for (;;){
        unsigned long long a = __hip_atomic_load(src,   __ATOMIC_RELAXED, __HIP_MEMORY_SCOPE_AGENT);
        unsigned long long b = __hip_atomic_load(src+1, __ATOMIC_RELAXED, __HIP_MEMORY_SCOPE_AGENT);
        if (((a & 0xFFFFu) == need) && (((a >> 32) & 0xFFFFu) == need) &&
            ((b & 0xFFFFu) == need) && (((b >> 32) & 0xFFFFu) == need)){
          pv[0] = (unsigned int)a; pv[1] = (unsigned int)(a >> 32);
          pv[2] = (unsigned int)b; pv[3] = (unsigned int)(b >> 32);
          break;
        }
      }
      // scatter partner h into A_s[buf] partner cols
      int base = tid*4;
      #pragma unroll
      for (int i = 0; i < 4; ++i){
        int f = base + i;
        A_s[buf][(f >> 7)*AS + p*128 + (f & 127)] = (unsigned short)(pv[i] >> 16);
      }
    }
    // stage x_{t+1}
    if (tid < 128 && (t+1) < Tn){
      int m = tid >> 3, ch = tid & 7;
      *(ushort8*)&A_s[nbuf][m*AS + Un + ch*8] = *(ushort8*)xv;
    }
    __syncthreads();   // barrier A: partner cols + staged x visible

    // (4) MFMA partner-h (slots 6..9)
    {
      const int kb = p*4;
      #pragma unroll
      for (int i = 0; i < 4; ++i){
        bf16x8 af = *(const bf16x8*)&A_s[buf][l15*AS + (kb + i)*32 + q*8];
        #pragma unroll
        for (int nt = 0; nt < 4; ++nt)
          acc[nt] = __builtin_amdgcn_mfma_f32_16x16x32_bf16(af, wfrag[6+i][nt], acc[nt], 0, 0, 0);
      }
    }

    // (5) gates; write own h^{t+1} to LDS; publish tagged words
    {
      const unsigned int tag = (unsigned int)((t+1) & 0xFFFF);
      unsigned int* dstb = xc_me + (size_t)((t+1) & 1)*2048;
      const int u_loc = w*16 + l15;
      #pragma unroll
      for (int r = 0; r < 4; ++r){
        float ig = sigm(acc[0][r]);
        float fg = sigm(acc[1][r]);
        float gg = tanh_f(acc[2][r]);
        float og = sigm(acc[3][r]);
        float cn = fg * c[r] + ig * gg;
        c[r] = cn;
        unsigned short hb = f2bf(og * tanh_f(cn));
        A_s[nbuf][(q*4 + r)*AS + (s*128 + u_loc)] = hb;
        __hip_atomic_store(dstb + (q*4 + r)*128 + u_loc,
                           ((unsigned int)hb << 16) | tag,
                           __ATOMIC_RELAXED, __HIP_MEMORY_SCOPE_AGENT);
      }
    }
    __syncthreads();   // barrier B: own cols of A_s[nbuf] ready for next step
  }

  // ---- epilogue: half-0 blocks assemble h_T, compute dot, write output ----
  if (s == 0){
    {
      const unsigned long long* src =
          (const unsigned long long*)(xc_pr + /*slot0*/ (size_t)0 + tid*4);
      const unsigned long long need = (unsigned long long)(Tn & 0xFFFF);
      unsigned int pv[4];
      for (;;){
        unsigned long long a = __hip_atomic_load(src,   __ATOMIC_RELAXED, __HIP_MEMORY_SCOPE_AGENT);
        unsigned long long b = __hip_atomic_load(src+1, __ATOMIC_RELAXED, __HIP_MEMORY_SCOPE_AGENT);
        if (((a & 0xFFFFu) == need) && (((a >> 32) & 0xFFFFu) == need) &&
            ((b & 0xFFFFu) == need) && (((b >> 32) & 0xFFFFu) == need)){
          pv[0] = (unsigned int)a; pv[1] = (unsigned int)(a >> 32);
          pv[2] = (unsigned int)b; pv[3] = (unsigned int)(b >> 32);
          break;
        }
      }
      int base = tid*4;
      #pragma unroll
      for (int i = 0; i < 4; ++i){
        int f = base + i;
        A_s[0][(f >> 7)*AS + 128 + (f & 127)] = (unsigned short)(pv[i] >> 16);
      }
    }
    __syncthreads();

    int m = tid >> 5, j = tid & 31;
    float partial = 0.f;
    for (int u = j; u < 256; u += 32)
      partial += bf2f(A_s[0][m*AS + u]) * load_f(dense_w, u, isf32);
    #pragma unroll
    for (int off = 1; off < 32; off <<= 1) partial += __shfl_xor(partial, off);
    if (j == 0) outv[m] = sigm(partial + load_f(dense_b, 0, isf32));
    __syncthreads();

    for (int mm = 0; mm < 16; ++mm){
      float v = outv[mm];
      long base = (long)(g*16 + mm) * Tn;
      for (int col = tid; col < Tn; col += THREADS){
        if (isf32) ((float*)out)[base + col] = v;
        else       ((unsigned short*)out)[base + col] = f2bf(v);
      }
    }
  }
}

// ---------------------------------------------------------------------------
extern "C" void kernel_launch(void* const* d_in, const int* in_sizes, int n_in,
                              void* d_out, int out_size, void* d_ws, size_t ws_size,
                              hipStream_t stream){
  const void* x  = d_in[0];
  const void* W  = d_in[1];
  const void* Uh = d_in[2];
  const void* b  = d_in[3];
  const void* dw = d_in[4];
  const void* db = d_in[5];

  int* wsi = (int*)d_ws;
  const int* dt = wsi;
  unsigned int* xchg = (unsigned int*)((char*)d_ws + WS_XCHG);
  unsigned short* Bp = (unsigned short*)((char*)d_ws + WS_BP);

  init_k<<<1, 64, 0, stream>>>(x, wsi);
  reformat_w<<<160, 256, 0, stream>>>(Uh, W, Bp, dt);
  lstm_k<<<GROUPS*2, THREADS, 0, stream>>>(x, b, dw, db, Bp, dt, xchg, d_out);
}

// Round 4
// 2992.092 us; speedup vs baseline: 3.8311x; 1.0016x over previous
//
#include <hip/hip_runtime.h>

#define Tn 1024
#define Fn 64
#define Un 256
#define Gn 1024
#define AS 328       // padded A row stride (ushorts)
#define GROUPS 32
#define THREADS 256

typedef __attribute__((ext_vector_type(8))) short bf16x8;
typedef __attribute__((ext_vector_type(8))) unsigned short ushort8;
typedef __attribute__((ext_vector_type(4))) float f32x4;

// ws layout (bytes):
//   [0, 4096)            : int hdr — dtype flag at int index 0
//   [4096, 4096+1048576) : xchg — 128 blocks x 2 parity x 1024 tagged u32
//                          (value = bf16<<16 | step-tag)
//   [WS_BP, +655360)     : packed weights Bp
#define WS_XCHG 4096
#define WS_BP   (WS_XCHG + 128*2*4096)

__device__ __forceinline__ float bf2f(unsigned short u){
  union { unsigned int i; float f; } v; v.i = ((unsigned int)u) << 16; return v.f;
}
__device__ __forceinline__ unsigned short f2bf(float f){
  unsigned int u = __float_as_uint(f);
  u += 0x7FFFu + ((u >> 16) & 1u);
  return (unsigned short)(u >> 16);
}
__device__ __forceinline__ float load_f(const void* p, long idx, int isf32){
  if (isf32) return ((const float*)p)[idx];
  return bf2f(((const unsigned short*)p)[idx]);
}
__device__ __forceinline__ float sigm(float x){ return 1.0f / (1.0f + __expf(-x)); }
__device__ __forceinline__ float tanh_f(float x){ return 2.0f * sigm(2.0f * x) - 1.0f; }

// ---------------------------------------------------------------------------
__global__ void init_k(const void* x, int* wsi){
  int tid = threadIdx.x;
  if (tid < 64){
    int cnt = 0;
    for (int s2 = 0; s2 < 4; ++s2){
      float v = bf2f(((const unsigned short*)x)[tid + 64*s2]);
      if (!(fabsf(v) <= 100.0f)) cnt++;
    }
    for (int off = 32; off > 0; off >>= 1) cnt += __shfl_down(cnt, off);
    if (tid == 0) wsi[0] = (cnt > 32) ? 1 : 0;   // 1 => inputs are fp32
  }
}

// ---------------------------------------------------------------------------
// pack [Uh; W] (K=320 x 1024) into B-fragment order. Column permutation for
// 4-way split: packed n: s=n>>8, w=(n>>6)&3, g=(n>>4)&3, ul=n&15
//   -> orig col = g*256 + s*64 + w*16 + ul
// (block s, wave w owns all 4 gates of units s*64 + w*16 .. +16)
__global__ void reformat_w(const void* Uh, const void* W, unsigned short* Bp, const int* dt){
  int isf32 = *dt;
  int gidx = blockIdx.x * blockDim.x + threadIdx.x;
  if (gidx >= 40960) return;
  int kt  = gidx >> 12;
  int rem = gidx & 4095;
  int n   = rem >> 2;
  int q   = rem & 3;
  int s   = n >> 8;
  int w   = (n >> 6) & 3;
  int g   = (n >> 4) & 3;
  int ul  = n & 15;
  int col = g*256 + s*64 + w*16 + ul;
  unsigned short vals[8];
  #pragma unroll
  for (int j = 0; j < 8; ++j){
    int k = kt*32 + q*8 + j;
    float v = (k < Un) ? load_f(Uh, (long)k*Gn + col, isf32)
                       : load_f(W,  (long)(k-Un)*Gn + col, isf32);
    vals[j] = f2bf(v);
  }
  *(ushort8*)(Bp + (long)gidx * 8) = *(ushort8*)vals;
}

// ---------------------------------------------------------------------------
// Persistent LSTM, 128 blocks x 256 threads (4 waves, 1 wave/SIMD).
// Group g = bid>>2, slice s = bid&3 (units s*64..s*64+63, all 4 gates).
// All 160 KB of this block's weights live in VGPRs (wfrag[10][4]).
// Exchange: tag-in-data u32 chunks via IC, skew<=1 proof holds for 4 parties.
__global__ __launch_bounds__(THREADS, 1) void lstm_k(
    const void* x, const void* bvec, const void* dense_w, const void* dense_b,
    const unsigned short* Bp, const int* dt, unsigned int* xchg, void* out)
{
  __shared__ __align__(16) unsigned short A_s[2][16*AS];
  __shared__ float outv[16];

  const int isf32 = *dt;
  const int tid = threadIdx.x;
  const int w   = tid >> 6;       // wave 0..3
  const int l   = tid & 63;
  const int l15 = l & 15;
  const int q   = l >> 4;
  const int g   = blockIdx.x >> 2;
  const int s   = blockIdx.x & 3;

  // partner block ids and kt slots
  int plist[3];
  #pragma unroll
  for (int j = 0; j < 3; ++j) plist[j] = j + (j >= s ? 1 : 0);

  // ---- weights into registers ----
  // slot->kt: 0:2s 1:2s+1 (own h), 2:8 3:9 (x), 4+2j+i: 2*p+i (partner h)
  int ktp[10];
  ktp[0] = 2*s; ktp[1] = 2*s + 1; ktp[2] = 8; ktp[3] = 9;
  #pragma unroll
  for (int j = 0; j < 3; ++j){ ktp[4+2*j] = 2*plist[j]; ktp[5+2*j] = 2*plist[j] + 1; }

  const char* Bb = (const char*)Bp + (long)(l15*64 + q*16);
  const int nb = s*256 + w*64;    // this wave's packed-col base
  bf16x8 wfrag[10][4];
  #pragma unroll
  for (int i = 0; i < 10; ++i){
    #pragma unroll
    for (int gg = 0; gg < 4; ++gg)
      wfrag[i][gg] = *(const bf16x8*)(Bb + (long)(ktp[i]*1024 + nb + gg*16)*64);
  }

  // zero h region of buffer 0
  for (int i = tid; i < 16*Un; i += THREADS)
    A_s[0][(i >> 8)*AS + (i & 255)] = 0;

  // x_0 -> buffer 0 cols [256,320)
  if (tid < 128){
    int m = tid >> 3, ch = tid & 7;
    long src = ((long)(g*16 + m)*Tn + 0)*Fn + ch*8;
    unsigned short v[8];
    if (isf32){ for (int j = 0; j < 8; ++j) v[j] = f2bf(((const float*)x)[src + j]); }
    else      { *(ushort8*)v = *(const ushort8*)((const unsigned short*)x + src); }
    *(ushort8*)&A_s[0][m*AS + Un + ch*8] = *(ushort8*)v;
  }

  const int u_loc = w*16 + l15;          // unit within slice
  float bias[4];
  #pragma unroll
  for (int gg = 0; gg < 4; ++gg) bias[gg] = load_f(bvec, gg*256 + s*64 + u_loc, isf32);

  float c[4] = {0.f, 0.f, 0.f, 0.f};

  unsigned int* xc_me = xchg + (size_t)(g*4 + s) * 2048;

  __syncthreads();

  for (int t = 0; t < Tn; ++t){
    const int buf = t & 1, nbuf = buf ^ 1;

    // (1) x_{t+1} into regs (non-blocking)
    unsigned short xv[8];
    if (tid < 128 && (t+1) < Tn){
      int m = tid >> 3, ch = tid & 7;
      long src = ((long)(g*16 + m)*Tn + (t+1))*Fn + ch*8;
      if (isf32){ for (int j = 0; j < 8; ++j) xv[j] = f2bf(((const float*)x)[src + j]); }
      else      { *(ushort8*)xv = *(const ushort8*)((const unsigned short*)x + src); }
    }

    // (2) MFMA own-h (slots 0,1) + x (slots 2,3); bias folded into acc init
    f32x4 acc[4];
    #pragma unroll
    for (int gg = 0; gg < 4; ++gg)
      acc[gg] = (f32x4){bias[gg], bias[gg], bias[gg], bias[gg]};
    #pragma unroll
    for (int i = 0; i < 4; ++i){
      bf16x8 af = *(const bf16x8*)&A_s[buf][l15*AS + ktp[i]*32 + q*8];
      #pragma unroll
      for (int gg = 0; gg < 4; ++gg)
        acc[gg] = __builtin_amdgcn_mfma_f32_16x16x32_bf16(af, wfrag[i][gg], acc[gg], 0, 0, 0);
    }

    // (3) poll 3 partner chunks (tag == t), scatter into A_s[buf] partner cols
    if (t > 0){
      const unsigned int need = (unsigned int)(t & 0xFFFF);
      #pragma unroll
      for (int j = 0; j < 3; ++j){
        int p = plist[j];
        const unsigned long long* src =
            (const unsigned long long*)(xchg + (size_t)((g*4 + p)*2 + buf)*1024) + tid*2;
        unsigned long long a, b;
        for (;;){
          a = __hip_atomic_load(src,   __ATOMIC_RELAXED, __HIP_MEMORY_SCOPE_AGENT);
          b = __hip_atomic_load(src+1, __ATOMIC_RELAXED, __HIP_MEMORY_SCOPE_AGENT);
          if ((((unsigned int)a & 0xFFFFu) == need) && ((unsigned int)(a >> 32) & 0xFFFFu) == need &&
              (((unsigned int)b & 0xFFFFu) == need) && ((unsigned int)(b >> 32) & 0xFFFFu) == need)
            break;
        }
        // pack 4 bf16 (hi halves) -> one ds_write_b64
        unsigned long long hv = ((a >> 16) & 0xFFFFull)
                              | (((a >> 48) & 0xFFFFull) << 16)
                              | (((b >> 16) & 0xFFFFull) << 32)
                              | (((b >> 48) & 0xFFFFull) << 48);
        int row = tid >> 4, u0 = (tid & 15) * 4;
        *(unsigned long long*)&A_s[buf][row*AS + p*64 + u0] = hv;
      }
    }
    // stage x_{t+1}
    if (tid < 128 && (t+1) < Tn){
      int m = tid >> 3, ch = tid & 7;
      *(ushort8*)&A_s[nbuf][m*AS + Un + ch*8] = *(ushort8*)xv;
    }
    __syncthreads();   // barrier A: partner cols + staged x visible

    // (4) MFMA partner-h (slots 4..9)
    if (t > 0){
      #pragma unroll
      for (int i = 4; i < 10; ++i){
        bf16x8 af = *(const bf16x8*)&A_s[buf][l15*AS + ktp[i]*32 + q*8];
        #pragma unroll
        for (int gg = 0; gg < 4; ++gg)
          acc[gg] = __builtin_amdgcn_mfma_f32_16x16x32_bf16(af, wfrag[i][gg], acc[gg], 0, 0, 0);
      }
    }

    // (5) gates; write own h^{t+1} to LDS; publish tagged words
    {
      const unsigned int tag = (unsigned int)((t+1) & 0xFFFF);
      unsigned int* dstb = xc_me + (size_t)nbuf*1024;
      #pragma unroll
      for (int r = 0; r < 4; ++r){
        float ig = sigm(acc[0][r]);
        float fg = sigm(acc[1][r]);
        float gg = tanh_f(acc[2][r]);
        float og = sigm(acc[3][r]);
        float cn = fg * c[r] + ig * gg;
        c[r] = cn;
        unsigned short hb = f2bf(og * tanh_f(cn));
        A_s[nbuf][(q*4 + r)*AS + (s*64 + u_loc)] = hb;
        __hip_atomic_store(dstb + (q*4 + r)*64 + u_loc,
                           ((unsigned int)hb << 16) | tag,
                           __ATOMIC_RELAXED, __HIP_MEMORY_SCOPE_AGENT);
      }
    }
    __syncthreads();   // barrier B: A_s[nbuf] own+x ready for next step
  }

  // ---- epilogue: slice-0 blocks assemble h_T (in A_s[0]), dot, write out ----
  if (s == 0){
    const unsigned int need = (unsigned int)(Tn & 0xFFFF);
    #pragma unroll
    for (int j = 0; j < 3; ++j){
      int p = plist[j];
      const unsigned long long* src =
          (const unsigned long long*)(xchg + (size_t)((g*4 + p)*2 + 0)*1024) + tid*2;
      unsigned long long a, b;
      for (;;){
        a = __hip_atomic_load(src,   __ATOMIC_RELAXED, __HIP_MEMORY_SCOPE_AGENT);
        b = __hip_atomic_load(src+1, __ATOMIC_RELAXED, __HIP_MEMORY_SCOPE_AGENT);
        if ((((unsigned int)a & 0xFFFFu) == need) && ((unsigned int)(a >> 32) & 0xFFFFu) == need &&
            (((unsigned int)b & 0xFFFFu) == need) && ((unsigned int)(b >> 32) & 0xFFFFu) == need)
          break;
      }
      unsigned long long hv = ((a >> 16) & 0xFFFFull)
                            | (((a >> 48) & 0xFFFFull) << 16)
                            | (((b >> 16) & 0xFFFFull) << 32)
                            | (((b >> 48) & 0xFFFFull) << 48);
      int row = tid >> 4, u0 = (tid & 15) * 4;
      *(unsigned long long*)&A_s[0][row*AS + p*64 + u0] = hv;
    }
    __syncthreads();

    int m = tid >> 4, j16 = tid & 15;
    float partial = 0.f;
    for (int u = j16; u < 256; u += 16)
      partial += bf2f(A_s[0][m*AS + u]) * load_f(dense_w, u, isf32);
    #pragma unroll
    for (int off = 1; off < 16; off <<= 1) partial += __shfl_xor(partial, off);
    if (j16 == 0) outv[m] = sigm(partial + load_f(dense_b, 0, isf32));
    __syncthreads();

    for (int mm = 0; mm < 16; ++mm){
      float v = outv[mm];
      long base = (long)(g*16 + mm) * Tn;
      for (int col = tid; col < Tn; col += THREADS){
        if (isf32) ((float*)out)[base + col] = v;
        else       ((unsigned short*)out)[base + col] = f2bf(v);
      }
    }
  }
}

// ---------------------------------------------------------------------------
extern "C" void kernel_launch(void* const* d_in, const int* in_sizes, int n_in,
                              void* d_out, int out_size, void* d_ws, size_t ws_size,
                              hipStream_t stream){
  const void* x  = d_in[0];
  const void* W  = d_in[1];
  const void* Uh = d_in[2];
  const void* b  = d_in[3];
  const void* dw = d_in[4];
  const void* db = d_in[5];

  int* wsi = (int*)d_ws;
  const int* dt = wsi;
  unsigned int* xchg = (unsigned int*)((char*)d_ws + WS_XCHG);
  unsigned short* Bp = (unsigned short*)((char*)d_ws + WS_BP);

  init_k<<<1, 64, 0, stream>>>(x, wsi);
  reformat_w<<<160, 256, 0, stream>>>(Uh, W, Bp, dt);
  lstm_k<<<GROUPS*4, THREADS, 0, stream>>>(x, b, dw, db, Bp, dt, xchg, d_out);
}

// Round 7
// 2792.816 us; speedup vs baseline: 4.1044x; 1.0714x over previous
//
#include <hip/hip_runtime.h>

#define Tn 1024
#define Fn 64
#define Un 256
#define Gn 1024
#define AS 328       // padded A row stride (ushorts)
#define THREADS 256
#define NB 128       // lstm blocks

typedef __attribute__((ext_vector_type(8))) short bf16x8;
typedef __attribute__((ext_vector_type(8))) unsigned short ushort8;
typedef __attribute__((ext_vector_type(4))) float f32x4;
typedef unsigned long long u64;

// ws layout (bytes):
//   [0, 4096)            : int hdr — [0]=dtype flag
//   [4096, 4096+1048576) : xchg — NB x 2 parity x 1024 tagged u32
//                          (value = bf16<<16 | step-tag)
//   [WS_BP, +655360)     : packed weights Bp
#define WS_XCHG 4096
#define WS_BP   (WS_XCHG + NB*2*4096)

__device__ __forceinline__ float bf2f(unsigned short u){
  union { unsigned int i; float f; } v; v.i = ((unsigned int)u) << 16; return v.f;
}
__device__ __forceinline__ unsigned short f2bf(float f){
  unsigned int u = __float_as_uint(f);
  u += 0x7FFFu + ((u >> 16) & 1u);
  return (unsigned short)(u >> 16);
}
__device__ __forceinline__ float load_f(const void* p, long idx, int isf32){
  if (isf32) return ((const float*)p)[idx];
  return bf2f(((const unsigned short*)p)[idx]);
}
__device__ __forceinline__ float sigm(float x){ return 1.0f / (1.0f + __expf(-x)); }
__device__ __forceinline__ float tanh_f(float x){ return 2.0f * sigm(2.0f * x) - 1.0f; }

__device__ __forceinline__ u64 ld_a64(const u64* p){
  return __hip_atomic_load(p, __ATOMIC_RELAXED, __HIP_MEMORY_SCOPE_AGENT);
}
__device__ __forceinline__ int ok64(u64 v, unsigned int need){
  return (int)(((unsigned int)v & 0xFFFFu) == need) &
         (int)(((unsigned int)(v >> 32) & 0xFFFFu) == need);
}

// ---------------------------------------------------------------------------
__global__ void init_k(const void* x, int* wsi){
  int tid = threadIdx.x;
  if (tid < 64){
    int cnt = 0;
    for (int s2 = 0; s2 < 4; ++s2){
      float v = bf2f(((const unsigned short*)x)[tid + 64*s2]);
      if (!(fabsf(v) <= 100.0f)) cnt++;
    }
    for (int off = 32; off > 0; off >>= 1) cnt += __shfl_down(cnt, off);
    if (tid == 0) wsi[0] = (cnt > 32) ? 1 : 0;   // 1 => inputs are fp32
  }
}

// ---------------------------------------------------------------------------
// pack [Uh; W] (K=320 x 1024) into B-fragment order. 4-way split permutation:
//   packed n: s=n>>8, w=(n>>6)&3, g=(n>>4)&3, ul=n&15
//   -> orig col = g*256 + s*64 + w*16 + ul
__global__ void reformat_w(const void* Uh, const void* W, unsigned short* Bp, const int* dt){
  int isf32 = *dt;
  int gidx = blockIdx.x * blockDim.x + threadIdx.x;
  if (gidx >= 40960) return;
  int kt  = gidx >> 12;
  int rem = gidx & 4095;
  int n   = rem >> 2;
  int q   = rem & 3;
  int s   = n >> 8;
  int w   = (n >> 6) & 3;
  int g   = (n >> 4) & 3;
  int ul  = n & 15;
  int col = g*256 + s*64 + w*16 + ul;
  unsigned short vals[8];
  #pragma unroll
  for (int j = 0; j < 8; ++j){
    int k = kt*32 + q*8 + j;
    float v = (k < Un) ? load_f(Uh, (long)k*Gn + col, isf32)
                       : load_f(W,  (long)(k-Un)*Gn + col, isf32);
    vals[j] = f2bf(v);
  }
  *(ushort8*)(Bp + (long)gidx * 8) = *(ushort8*)vals;
}

// ---------------------------------------------------------------------------
// Persistent LSTM, 128 blocks x 256 threads (round-4 proven structure).
// Group g = bid>>2, slice s = bid&3 (units s*64..s*64+63, all 4 gates).
// Weights VGPR/AGPR-resident. Exchange: tag-in-data agent-scope u64 loads,
// ALL SIX partner words issued concurrently (one RT), pre-issued before the
// own-MFMA phase so the first round trip hides under MFMA issue/execute.
__global__ __launch_bounds__(THREADS, 1) void lstm_k(
    const void* x, const void* bvec, const void* dense_w, const void* dense_b,
    const unsigned short* Bp, const int* dt, unsigned int* xchg, void* out)
{
  __shared__ __align__(16) unsigned short A_s[2][16*AS];
  __shared__ float outv[16];

  const int isf32 = *dt;
  const int tid = threadIdx.x;
  const int w   = tid >> 6;
  const int l   = tid & 63;
  const int l15 = l & 15;
  const int q   = l >> 4;
  const int g   = blockIdx.x >> 2;
  const int s   = blockIdx.x & 3;

  int plist[3];
  #pragma unroll
  for (int j = 0; j < 3; ++j) plist[j] = j + (j >= s ? 1 : 0);

  // ---- weights into registers ----
  int ktp[10];
  ktp[0] = 2*s; ktp[1] = 2*s + 1; ktp[2] = 8; ktp[3] = 9;
  #pragma unroll
  for (int j = 0; j < 3; ++j){ ktp[4+2*j] = 2*plist[j]; ktp[5+2*j] = 2*plist[j] + 1; }

  const char* Bb = (const char*)Bp + (long)(l15*64 + q*16);
  const int nb = s*256 + w*64;
  bf16x8 wfrag[10][4];
  #pragma unroll
  for (int i = 0; i < 10; ++i){
    #pragma unroll
    for (int gg = 0; gg < 4; ++gg)
      wfrag[i][gg] = *(const bf16x8*)(Bb + (long)(ktp[i]*1024 + nb + gg*16)*64);
  }

  // zero h region of buffer 0
  for (int i = tid; i < 16*Un; i += THREADS)
    A_s[0][(i >> 8)*AS + (i & 255)] = 0;

  // x_0 -> buffer 0 cols [256,320)
  if (tid < 128){
    int m = tid >> 3, ch = tid & 7;
    long src = ((long)(g*16 + m)*Tn + 0)*Fn + ch*8;
    unsigned short v[8];
    if (isf32){ for (int j = 0; j < 8; ++j) v[j] = f2bf(((const float*)x)[src + j]); }
    else      { *(ushort8*)v = *(const ushort8*)((const unsigned short*)x + src); }
    *(ushort8*)&A_s[0][m*AS + Un + ch*8] = *(ushort8*)v;
  }

  const int u_loc = w*16 + l15;
  float bias[4];
  #pragma unroll
  for (int gg = 0; gg < 4; ++gg) bias[gg] = load_f(bvec, gg*256 + s*64 + u_loc, isf32);

  float c[4] = {0.f, 0.f, 0.f, 0.f};
  unsigned int* xc_me = xchg + (size_t)(g*4 + s) * 2048;

  // per-thread partner poll addresses (recomputed parity offset per step)
  const u64* pa[3];
  #pragma unroll
  for (int j = 0; j < 3; ++j)
    pa[j] = (const u64*)(xchg + (size_t)((g*4 + plist[j])*2)*1024) + tid*2;

  __syncthreads();

  for (int t = 0; t < Tn; ++t){
    const int buf = t & 1, nbuf = buf ^ 1;
    const size_t po = (size_t)buf * 512;   // parity offset in u64s

    // (1) x_{t+1} into regs
    unsigned short xv[8];
    if (tid < 128 && (t+1) < Tn){
      int m = tid >> 3, ch = tid & 7;
      long src = ((long)(g*16 + m)*Tn + (t+1))*Fn + ch*8;
      if (isf32){ for (int j = 0; j < 8; ++j) xv[j] = f2bf(((const float*)x)[src + j]); }
      else      { *(ushort8*)xv = *(const ushort8*)((const unsigned short*)x + src); }
    }

    // (1b) PRE-ISSUE all six partner tag-loads (fly under the MFMA phase)
    u64 pw[6];
    if (t > 0){
      pw[0] = ld_a64(pa[0] + po);  pw[1] = ld_a64(pa[0] + po + 1);
      pw[2] = ld_a64(pa[1] + po);  pw[3] = ld_a64(pa[1] + po + 1);
      pw[4] = ld_a64(pa[2] + po);  pw[5] = ld_a64(pa[2] + po + 1);
    }

    // (2) MFMA own-h + x; bias folded into acc init
    f32x4 acc[4];
    #pragma unroll
    for (int gg = 0; gg < 4; ++gg)
      acc[gg] = (f32x4){bias[gg], bias[gg], bias[gg], bias[gg]};
    #pragma unroll
    for (int i = 0; i < 4; ++i){
      bf16x8 af = *(const bf16x8*)&A_s[buf][l15*AS + ktp[i]*32 + q*8];
      #pragma unroll
      for (int gg = 0; gg < 4; ++gg)
        acc[gg] = __builtin_amdgcn_mfma_f32_16x16x32_bf16(af, wfrag[i][gg], acc[gg], 0, 0, 0);
    }

    // (3) tag-check; if any not ready, spin re-issuing ALL SIX concurrently
    if (t > 0){
      const unsigned int need = (unsigned int)(t & 0xFFFF);
      while (!(ok64(pw[0], need) & ok64(pw[1], need) & ok64(pw[2], need) &
               ok64(pw[3], need) & ok64(pw[4], need) & ok64(pw[5], need))){
        pw[0] = ld_a64(pa[0] + po);  pw[1] = ld_a64(pa[0] + po + 1);
        pw[2] = ld_a64(pa[1] + po);  pw[3] = ld_a64(pa[1] + po + 1);
        pw[4] = ld_a64(pa[2] + po);  pw[5] = ld_a64(pa[2] + po + 1);
      }
      // scatter partner h into A_s[buf] partner cols (one ds_write_b64 each)
      const int row = tid >> 4, u0c = (tid & 15) * 4;
      #pragma unroll
      for (int j = 0; j < 3; ++j){
        u64 a = pw[2*j], b = pw[2*j + 1];
        u64 hv = ((a >> 16) & 0xFFFFull)
               | (((a >> 48) & 0xFFFFull) << 16)
               | (((b >> 16) & 0xFFFFull) << 32)
               | (((b >> 48) & 0xFFFFull) << 48);
        *(u64*)&A_s[buf][row*AS + plist[j]*64 + u0c] = hv;
      }
    }
    // stage x_{t+1}
    if (tid < 128 && (t+1) < Tn){
      int m = tid >> 3, ch = tid & 7;
      *(ushort8*)&A_s[nbuf][m*AS + Un + ch*8] = *(ushort8*)xv;
    }
    __syncthreads();   // barrier A: partner cols + staged x visible

    // (4) MFMA partner-h
    if (t > 0){
      #pragma unroll
      for (int i = 4; i < 10; ++i){
        bf16x8 af = *(const bf16x8*)&A_s[buf][l15*AS + ktp[i]*32 + q*8];
        #pragma unroll
        for (int gg = 0; gg < 4; ++gg)
          acc[gg] = __builtin_amdgcn_mfma_f32_16x16x32_bf16(af, wfrag[i][gg], acc[gg], 0, 0, 0);
      }
    }

    // (5) gates; own h to LDS; publish tagged words
    {
      const unsigned int tag = (unsigned int)((t+1) & 0xFFFF);
      unsigned int* dstb = xc_me + (size_t)nbuf*1024;
      #pragma unroll
      for (int r = 0; r < 4; ++r){
        float ig = sigm(acc[0][r]);
        float fg = sigm(acc[1][r]);
        float gg = tanh_f(acc[2][r]);
        float og = sigm(acc[3][r]);
        float cn = fg * c[r] + ig * gg;
        c[r] = cn;
        unsigned short hb = f2bf(og * tanh_f(cn));
        A_s[nbuf][(q*4 + r)*AS + (s*64 + u_loc)] = hb;
        __hip_atomic_store(dstb + (q*4 + r)*64 + u_loc,
                           ((unsigned int)hb << 16) | tag,
                           __ATOMIC_RELAXED, __HIP_MEMORY_SCOPE_AGENT);
      }
    }
    __syncthreads();   // barrier B: A_s[nbuf] own+x ready for next step
  }

  // ---- epilogue: slice-0 blocks assemble h_T, dot, write out ----
  if (s == 0){
    const unsigned int need = (unsigned int)(Tn & 0xFFFF);
    u64 pw[6];
    pw[0] = ld_a64(pa[0]);  pw[1] = ld_a64(pa[0] + 1);
    pw[2] = ld_a64(pa[1]);  pw[3] = ld_a64(pa[1] + 1);
    pw[4] = ld_a64(pa[2]);  pw[5] = ld_a64(pa[2] + 1);
    while (!(ok64(pw[0], need) & ok64(pw[1], need) & ok64(pw[2], need) &
             ok64(pw[3], need) & ok64(pw[4], need) & ok64(pw[5], need))){
      pw[0] = ld_a64(pa[0]);  pw[1] = ld_a64(pa[0] + 1);
      pw[2] = ld_a64(pa[1]);  pw[3] = ld_a64(pa[1] + 1);
      pw[4] = ld_a64(pa[2]);  pw[5] = ld_a64(pa[2] + 1);
    }
    const int row = tid >> 4, u0c = (tid & 15) * 4;
    #pragma unroll
    for (int j = 0; j < 3; ++j){
      u64 a = pw[2*j], b = pw[2*j + 1];
      u64 hv = ((a >> 16) & 0xFFFFull)
             | (((a >> 48) & 0xFFFFull) << 16)
             | (((b >> 16) & 0xFFFFull) << 32)
             | (((b >> 48) & 0xFFFFull) << 48);
      *(u64*)&A_s[0][row*AS + plist[j]*64 + u0c] = hv;
    }
    __syncthreads();

    int m = tid >> 4, j16 = tid & 15;
    float partial = 0.f;
    for (int u = j16; u < 256; u += 16)
      partial += bf2f(A_s[0][m*AS + u]) * load_f(dense_w, u, isf32);
    #pragma unroll
    for (int off = 1; off < 16; off <<= 1) partial += __shfl_xor(partial, off);
    if (j16 == 0) outv[m] = sigm(partial + load_f(dense_b, 0, isf32));
    __syncthreads();

    for (int mm = 0; mm < 16; ++mm){
      float v = outv[mm];
      long base = (long)(g*16 + mm) * Tn;
      for (int col = tid; col < Tn; col += THREADS){
        if (isf32) ((float*)out)[base + col] = v;
        else       ((unsigned short*)out)[base + col] = f2bf(v);
      }
    }
  }
}

// ---------------------------------------------------------------------------
extern "C" void kernel_launch(void* const* d_in, const int* in_sizes, int n_in,
                              void* d_out, int out_size, void* d_ws, size_t ws_size,
                              hipStream_t stream){
  const void* x  = d_in[0];
  const void* W  = d_in[1];
  const void* Uh = d_in[2];
  const void* b  = d_in[3];
  const void* dw = d_in[4];
  const void* db = d_in[5];

  int* hdr = (int*)d_ws;
  unsigned int* xchg = (unsigned int*)((char*)d_ws + WS_XCHG);
  unsigned short* Bp = (unsigned short*)((char*)d_ws + WS_BP);

  init_k<<<1, 64, 0, stream>>>(x, hdr);
  reformat_w<<<160, 256, 0, stream>>>(Uh, W, Bp, hdr);
  lstm_k<<<NB, THREADS, 0, stream>>>(x, b, dw, db, Bp, hdr, xchg, d_out);
}